// Round 11
// baseline (728.528 us; speedup 1.0000x reference)
//
#include <hip/hip_runtime.h>

#define BS 256
#define HS 512
#define IN_DIM 64
#define OUT_DIM 4
#define BLKS_PER_B 8
#define ROWS_PER_BLK 64     // per block (8 blocks per b)
#define ROWS_PER_WAVE 16    // 4 waves per block

typedef float nfloat4 __attribute__((ext_vector_type(4)));  // for nt stores

// ---------------------------------------------------------------------------
// Single fused kernel, 2048 blocks x 256 threads, __launch_bounds__(256,8):
// VGPR<=64 -> 8 blocks/CU -> ALL blocks co-resident (spin-safe).
// Block blk: b = blk/8, owns rows i in [ (blk%8)*64 , +64 ).
//   Phase A: rec rows (1-row units, float4 streaming; installs hebb in cache)
//   handoff: atomicAdd(count[b]); last arriver computes act+heads+scale,
//            release-stores flag[b]; siblings acquire-spin (tid0 only).
//   Phase C: hebb_new = clip(hebb + scale*hidden) over own rows (reverse),
//            reads cache-hot (R6: FETCH == one pass), nt stores.
// ---------------------------------------------------------------------------
__global__ __launch_bounds__(256, 8) void fused_kernel(
    const float* __restrict__ inputs,
    const float* __restrict__ hidden,
    const float* __restrict__ hebb,
    const float* __restrict__ Wi,  const float* __restrict__ bi,
    const float* __restrict__ w,   const float* __restrict__ alpha,
    const float* __restrict__ Wo,  const float* __restrict__ bo,
    const float* __restrict__ Wv,  const float* __restrict__ bv,
    const float* __restrict__ Wda, const float* __restrict__ bda,
    float* __restrict__ activout, float* __restrict__ valueout,
    float* __restrict__ daout,    float* __restrict__ hactiv,
    float* __restrict__ hebb_new,
    float* __restrict__ rs,        // [BS*HS]: rec, then overwritten by scale
    int* __restrict__ count,       // [BS], zeroed each call
    int* __restrict__ flag)        // [BS], zeroed each call
{
    const int tid  = threadIdx.x;
    const int lane = tid & 63;
    const int wave = tid >> 6;
    const int blk  = blockIdx.x;
    const int b    = blk >> 3;
    const int ibase = (blk & 7) * ROWS_PER_BLK + wave * ROWS_PER_WAVE;

    __shared__ __align__(16) float sh_in[IN_DIM];
    __shared__ float red[4][6];
    __shared__ float da_sh;
    __shared__ int s_last;

    const size_t brow = (size_t)b * HS;
    const float4* __restrict__ h4 = (const float4*)(hidden + brow);
    const float4 hh0 = h4[lane];
    const float4 hh1 = h4[lane + 64];

    // ---------------- Phase A: rec rows ----------------
    for (int u = 0; u < ROWS_PER_WAVE; ++u) {
        const int i0 = ibase + u;
        const size_t row = brow + i0;
        const float4* __restrict__ hb4 = (const float4*)(hebb + row * HS);
        const float4* __restrict__ w4  = (const float4*)(w     + (size_t)i0 * HS);
        const float4* __restrict__ a4  = (const float4*)(alpha + (size_t)i0 * HS);

        const float4 hb0 = hb4[lane];
        const float4 hb1 = hb4[lane + 64];
        const float4 ww0 = w4[lane];
        const float4 ww1 = w4[lane + 64];
        const float4 aa0 = a4[lane];
        const float4 aa1 = a4[lane + 64];

        float s = 0.f;
        s += hh0.x * (ww0.x + aa0.x * hb0.x);
        s += hh0.y * (ww0.y + aa0.y * hb0.y);
        s += hh0.z * (ww0.z + aa0.z * hb0.z);
        s += hh0.w * (ww0.w + aa0.w * hb0.w);
        s += hh1.x * (ww1.x + aa1.x * hb1.x);
        s += hh1.y * (ww1.y + aa1.y * hb1.y);
        s += hh1.z * (ww1.z + aa1.z * hb1.z);
        s += hh1.w * (ww1.w + aa1.w * hb1.w);
#pragma unroll
        for (int off = 32; off > 0; off >>= 1)
            s += __shfl_xor(s, off, 64);
        if (lane == 0) rs[row] = s;
    }

    // ---------------- handoff ----------------
    __syncthreads();   // all waves' rec stores issued (drained to L2)
    if (tid == 0) {
        const int prev = __hip_atomic_fetch_add(&count[b], 1, __ATOMIC_ACQ_REL,
                                                __HIP_MEMORY_SCOPE_AGENT);
        s_last = (prev == BLKS_PER_B - 1);
    }
    __syncthreads();

    if (s_last) {
        // -------- act + heads + scale for this b (one block) --------
        if (tid < IN_DIM) sh_in[tid] = inputs[b * IN_DIM + tid];
        __syncthreads();

        float h[2];
        float p[6] = {0.f, 0.f, 0.f, 0.f, 0.f, 0.f};
#pragma unroll
        for (int r = 0; r < 2; ++r) {
            const int i = tid + r * 256;
            float dot = 0.f;
            const float4* __restrict__ wi4 = (const float4*)(Wi + (size_t)i * IN_DIM);
#pragma unroll
            for (int t = 0; t < IN_DIM / 4; ++t) {
                const float4 a = wi4[t];
                const float4 x = ((const float4*)sh_in)[t];
                dot += a.x * x.x + a.y * x.y + a.z * x.z + a.w * x.w;
            }
            h[r] = tanhf(dot + bi[i] + rs[brow + i]);
            hactiv[brow + i] = h[r];
            p[0] += h[r] * Wo[0 * HS + i];
            p[1] += h[r] * Wo[1 * HS + i];
            p[2] += h[r] * Wo[2 * HS + i];
            p[3] += h[r] * Wo[3 * HS + i];
            p[4] += h[r] * Wv[i];
            p[5] += h[r] * Wda[i];
        }
#pragma unroll
        for (int k = 0; k < 6; ++k) {
            float s = p[k];
#pragma unroll
            for (int off = 32; off > 0; off >>= 1)
                s += __shfl_xor(s, off, 64);
            if (lane == 0) red[wave][k] = s;
        }
        __syncthreads();
        if (tid < 6) {
            float s = red[0][tid] + red[1][tid] + red[2][tid] + red[3][tid];
            if (tid < 4) {
                activout[b * OUT_DIM + tid] = s + bo[tid];
            } else if (tid == 4) {
                valueout[b] = s + bv[0];
            } else {
                const float da = tanhf(s + bda[0]);
                daout[b] = da;
                da_sh = da;
            }
        }
        __syncthreads();
        const float da = da_sh;
        rs[brow + tid]       = da * h[0];   // scale overwrites rec
        rs[brow + tid + 256] = da * h[1];
        __syncthreads();   // all scale stores drained before release
        if (tid == 0)
            __hip_atomic_store(&flag[b], 1, __ATOMIC_RELEASE,
                               __HIP_MEMORY_SCOPE_AGENT);
    } else {
        if (tid == 0) {
            while (__hip_atomic_load(&flag[b], __ATOMIC_ACQUIRE,
                                     __HIP_MEMORY_SCOPE_AGENT) == 0)
                __builtin_amdgcn_s_sleep(8);
        }
        __syncthreads();
    }

    // ---------------- Phase C: hebb update over own rows (reverse) ----------------
    for (int u = ROWS_PER_WAVE - 1; u >= 0; --u) {
        const int i0 = ibase + u;
        const size_t row = brow + i0;
        const float sc = rs[row];
        const float4* __restrict__ hb4 = (const float4*)(hebb + row * HS);
        nfloat4* __restrict__ dst = (nfloat4*)(hebb_new + row * HS);

        const float4 hb0 = hb4[lane];
        const float4 hb1 = hb4[lane + 64];
        nfloat4 o0, o1;
        o0.x = fminf(fmaxf(hb0.x + sc * hh0.x, -1.f), 1.f);
        o0.y = fminf(fmaxf(hb0.y + sc * hh0.y, -1.f), 1.f);
        o0.z = fminf(fmaxf(hb0.z + sc * hh0.z, -1.f), 1.f);
        o0.w = fminf(fmaxf(hb0.w + sc * hh0.w, -1.f), 1.f);
        o1.x = fminf(fmaxf(hb1.x + sc * hh1.x, -1.f), 1.f);
        o1.y = fminf(fmaxf(hb1.y + sc * hh1.y, -1.f), 1.f);
        o1.z = fminf(fmaxf(hb1.z + sc * hh1.z, -1.f), 1.f);
        o1.w = fminf(fmaxf(hb1.w + sc * hh1.w, -1.f), 1.f);
        __builtin_nontemporal_store(o0, dst + lane);
        __builtin_nontemporal_store(o1, dst + lane + 64);
    }
}

extern "C" void kernel_launch(void* const* d_in, const int* in_sizes, int n_in,
                              void* d_out, int out_size, void* d_ws, size_t ws_size,
                              hipStream_t stream) {
    const float* inputs = (const float*)d_in[0];
    const float* hidden = (const float*)d_in[1];
    const float* hebb   = (const float*)d_in[2];
    const float* Wi     = (const float*)d_in[3];
    const float* bi     = (const float*)d_in[4];
    const float* w      = (const float*)d_in[5];
    const float* alpha  = (const float*)d_in[6];
    const float* Wo     = (const float*)d_in[7];
    const float* bo     = (const float*)d_in[8];
    const float* Wv     = (const float*)d_in[9];
    const float* bv     = (const float*)d_in[10];
    const float* Wda    = (const float*)d_in[11];
    const float* bda    = (const float*)d_in[12];

    float* out = (float*)d_out;
    float* activout = out;                       // [256,4]   = 1024
    float* valueout = out + 1024;                // [256,1]   = 256
    float* daout    = out + 1280;                // [256,1]   = 256
    float* hactiv   = out + 1536;                // [256,512] = 131072
    float* hebb_new = out + 1536 + BS * HS;      // [256,512,512]

    float* rs   = (float*)d_ws;                              // 512 KB
    int*  count = (int*)((char*)d_ws + (size_t)BS * HS * 4); // 1 KB
    int*  flag  = count + BS;                                // 1 KB

    // zero the sync region every call (graph-safe, deterministic)
    hipMemsetAsync(count, 0, 2 * BS * sizeof(int), stream);

    fused_kernel<<<2048, 256, 0, stream>>>(inputs, hidden, hebb, Wi, bi, w, alpha,
                                           Wo, bo, Wv, bv, Wda, bda,
                                           activout, valueout, daout, hactiv,
                                           hebb_new, rs, count, flag);
}

// Round 12
// 227.040 us; speedup vs baseline: 3.2088x; 3.2088x over previous
//
#include <hip/hip_runtime.h>

#define BS 256
#define HS 512
#define IN_DIM 64
#define OUT_DIM 4
#define BPB 4            // blocks per batch element
#define RPB 128          // rows per block
#define RPW 32           // rows per wave

typedef float nfloat4 __attribute__((ext_vector_type(4)));  // for nt stores

// ---------------------------------------------------------------------------
// Single fused kernel, 1024 blocks x 256 threads, __launch_bounds__(256,4):
// 4 blocks/CU co-resident with slack. Block blk: b = blk/4, owns 128 rows.
//  Phase A: per own row i: rec+Wi-dot in ONE butterfly reduce (total lands in
//           all lanes) -> hactiv[b,i] stored; 6 head partials accumulated
//           wave-uniformly; block partials -> acc[b][part][6] (no float atomics).
//  Handoff: int atomicAdd(count[b]); last block sums acc deterministically,
//           writes activout/valueout/daout, release-stores flag[b].
//           Waiters: RELAXED poll + one ACQUIRE load (single L1 inv).
//  Phase C: hebb_new = clip(hebb + DA*hactiv[i]*hidden[j]) over own rows;
//           hebb re-read is cache-served (R11: FETCH == one pass), nt stores.
// ---------------------------------------------------------------------------
__global__ __launch_bounds__(256, 4) void fused_kernel(
    const float* __restrict__ inputs,
    const float* __restrict__ hidden,
    const float* __restrict__ hebb,
    const float* __restrict__ Wi,  const float* __restrict__ bi,
    const float* __restrict__ w,   const float* __restrict__ alpha,
    const float* __restrict__ Wo,  const float* __restrict__ bo,
    const float* __restrict__ Wv,  const float* __restrict__ bv,
    const float* __restrict__ Wda, const float* __restrict__ bda,
    float* __restrict__ activout, float* __restrict__ valueout,
    float* __restrict__ daout,    float* __restrict__ hactiv,
    float* __restrict__ hebb_new,
    float* __restrict__ acc,       // [BS][BPB][6]
    int* __restrict__ count,       // [BS] zeroed each call
    int* __restrict__ flag)        // [BS] zeroed each call
{
    const int tid  = threadIdx.x;
    const int lane = tid & 63;
    const int wave = tid >> 6;
    const int blk  = blockIdx.x;
    const int b    = blk >> 2;
    const int part = blk & 3;
    const int ibase = part * RPB + wave * RPW;

    __shared__ float red[4][6];
    __shared__ int s_last;

    const size_t brow = (size_t)b * HS;
    const float4* __restrict__ h4 = (const float4*)(hidden + brow);
    const float4 hh0 = h4[lane];
    const float4 hh1 = h4[lane + 64];
    const float x_lane = inputs[b * IN_DIM + lane];   // IN_DIM == 64 == lanes

    // ---------------- Phase A ----------------
    float p0 = 0.f, p1 = 0.f, p2 = 0.f, p3 = 0.f, p4 = 0.f, p5 = 0.f;
    for (int u = 0; u < RPW; u += 2) {
        const int iA = ibase + u;
        const int iB = iA + 1;
        const float4* __restrict__ hbA4 = (const float4*)(hebb + (brow + iA) * HS);
        const float4* __restrict__ hbB4 = (const float4*)(hebb + (brow + iB) * HS);
        const float4* __restrict__ wA4  = (const float4*)(w     + (size_t)iA * HS);
        const float4* __restrict__ wB4  = (const float4*)(w     + (size_t)iB * HS);
        const float4* __restrict__ aA4  = (const float4*)(alpha + (size_t)iA * HS);
        const float4* __restrict__ aB4  = (const float4*)(alpha + (size_t)iB * HS);

        const float4 hbA0 = hbA4[lane];
        const float4 hbA1 = hbA4[lane + 64];
        const float4 hbB0 = hbB4[lane];
        const float4 hbB1 = hbB4[lane + 64];
        const float4 wwA0 = wA4[lane];
        const float4 wwA1 = wA4[lane + 64];
        const float4 wwB0 = wB4[lane];
        const float4 wwB1 = wB4[lane + 64];
        const float4 aaA0 = aA4[lane];
        const float4 aaA1 = aA4[lane + 64];
        const float4 aaB0 = aB4[lane];
        const float4 aaB1 = aB4[lane + 64];
        const float wiA = Wi[(size_t)iA * IN_DIM + lane];
        const float wiB = Wi[(size_t)iB * IN_DIM + lane];

        float sA = wiA * x_lane;
        sA += hh0.x * (wwA0.x + aaA0.x * hbA0.x);
        sA += hh0.y * (wwA0.y + aaA0.y * hbA0.y);
        sA += hh0.z * (wwA0.z + aaA0.z * hbA0.z);
        sA += hh0.w * (wwA0.w + aaA0.w * hbA0.w);
        sA += hh1.x * (wwA1.x + aaA1.x * hbA1.x);
        sA += hh1.y * (wwA1.y + aaA1.y * hbA1.y);
        sA += hh1.z * (wwA1.z + aaA1.z * hbA1.z);
        sA += hh1.w * (wwA1.w + aaA1.w * hbA1.w);

        float sB = wiB * x_lane;
        sB += hh0.x * (wwB0.x + aaB0.x * hbB0.x);
        sB += hh0.y * (wwB0.y + aaB0.y * hbB0.y);
        sB += hh0.z * (wwB0.z + aaB0.z * hbB0.z);
        sB += hh0.w * (wwB0.w + aaB0.w * hbB0.w);
        sB += hh1.x * (wwB1.x + aaB1.x * hbB1.x);
        sB += hh1.y * (wwB1.y + aaB1.y * hbB1.y);
        sB += hh1.z * (wwB1.z + aaB1.z * hbB1.z);
        sB += hh1.w * (wwB1.w + aaB1.w * hbB1.w);

#pragma unroll
        for (int off = 32; off > 0; off >>= 1) {
            sA += __shfl_xor(sA, off, 64);   // butterfly: total in ALL lanes
            sB += __shfl_xor(sB, off, 64);
        }

        const float hA = tanhf(sA + bi[iA]);   // wave-uniform broadcast loads
        const float hB = tanhf(sB + bi[iB]);
        if (lane == 0) {
            hactiv[brow + iA] = hA;
            hactiv[brow + iB] = hB;
        }
        p0 += hA * Wo[0 * HS + iA] + hB * Wo[0 * HS + iB];
        p1 += hA * Wo[1 * HS + iA] + hB * Wo[1 * HS + iB];
        p2 += hA * Wo[2 * HS + iA] + hB * Wo[2 * HS + iB];
        p3 += hA * Wo[3 * HS + iA] + hB * Wo[3 * HS + iB];
        p4 += hA * Wv[iA] + hB * Wv[iB];
        p5 += hA * Wda[iA] + hB * Wda[iB];
    }

    if (lane == 0) {
        red[wave][0] = p0; red[wave][1] = p1; red[wave][2] = p2;
        red[wave][3] = p3; red[wave][4] = p4; red[wave][5] = p5;
    }
    __syncthreads();
    if (tid < 6) {
        acc[(b * BPB + part) * 6 + tid] =
            red[0][tid] + red[1][tid] + red[2][tid] + red[3][tid];
    }
    __syncthreads();   // drains acc stores (compiler waitcnt before barrier)

    // ---------------- handoff ----------------
    if (tid == 0) {
        const int prev = __hip_atomic_fetch_add(&count[b], 1, __ATOMIC_ACQ_REL,
                                                __HIP_MEMORY_SCOPE_AGENT);
        s_last = (prev == BPB - 1);
    }
    __syncthreads();

    if (s_last) {
        if (tid < 6) {
            float s = acc[(b * BPB + 0) * 6 + tid]
                    + acc[(b * BPB + 1) * 6 + tid]
                    + acc[(b * BPB + 2) * 6 + tid]
                    + acc[(b * BPB + 3) * 6 + tid];
            if (tid < 4) {
                activout[b * OUT_DIM + tid] = s + bo[tid];
            } else if (tid == 4) {
                valueout[b] = s + bv[0];
            } else {
                daout[b] = tanhf(s + bda[0]);
            }
        }
        __syncthreads();   // drain daout store before release
        if (tid == 0)
            __hip_atomic_store(&flag[b], 1, __ATOMIC_RELEASE,
                               __HIP_MEMORY_SCOPE_AGENT);
    } else {
        if (tid == 0) {
            while (__hip_atomic_load(&flag[b], __ATOMIC_RELAXED,
                                     __HIP_MEMORY_SCOPE_AGENT) == 0)
                __builtin_amdgcn_s_sleep(16);
            (void)__hip_atomic_load(&flag[b], __ATOMIC_ACQUIRE,
                                    __HIP_MEMORY_SCOPE_AGENT);
        }
        __syncthreads();
    }

    const float DA = daout[b];   // uniform broadcast load

    // ---------------- Phase C ----------------
    for (int u = 0; u < RPW; u += 2) {
        const int iA = ibase + u;
        const int iB = iA + 1;
        const float scA = DA * hactiv[brow + iA];
        const float scB = DA * hactiv[brow + iB];
        const float4* __restrict__ hbA4 = (const float4*)(hebb + (brow + iA) * HS);
        const float4* __restrict__ hbB4 = (const float4*)(hebb + (brow + iB) * HS);
        nfloat4* __restrict__ dstA = (nfloat4*)(hebb_new + (brow + iA) * HS);
        nfloat4* __restrict__ dstB = (nfloat4*)(hebb_new + (brow + iB) * HS);

        const float4 hbA0 = hbA4[lane];
        const float4 hbA1 = hbA4[lane + 64];
        const float4 hbB0 = hbB4[lane];
        const float4 hbB1 = hbB4[lane + 64];

        nfloat4 o;
        o.x = fminf(fmaxf(hbA0.x + scA * hh0.x, -1.f), 1.f);
        o.y = fminf(fmaxf(hbA0.y + scA * hh0.y, -1.f), 1.f);
        o.z = fminf(fmaxf(hbA0.z + scA * hh0.z, -1.f), 1.f);
        o.w = fminf(fmaxf(hbA0.w + scA * hh0.w, -1.f), 1.f);
        __builtin_nontemporal_store(o, dstA + lane);
        o.x = fminf(fmaxf(hbA1.x + scA * hh1.x, -1.f), 1.f);
        o.y = fminf(fmaxf(hbA1.y + scA * hh1.y, -1.f), 1.f);
        o.z = fminf(fmaxf(hbA1.z + scA * hh1.z, -1.f), 1.f);
        o.w = fminf(fmaxf(hbA1.w + scA * hh1.w, -1.f), 1.f);
        __builtin_nontemporal_store(o, dstA + lane + 64);
        o.x = fminf(fmaxf(hbB0.x + scB * hh0.x, -1.f), 1.f);
        o.y = fminf(fmaxf(hbB0.y + scB * hh0.y, -1.f), 1.f);
        o.z = fminf(fmaxf(hbB0.z + scB * hh0.z, -1.f), 1.f);
        o.w = fminf(fmaxf(hbB0.w + scB * hh0.w, -1.f), 1.f);
        __builtin_nontemporal_store(o, dstB + lane);
        o.x = fminf(fmaxf(hbB1.x + scB * hh1.x, -1.f), 1.f);
        o.y = fminf(fmaxf(hbB1.y + scB * hh1.y, -1.f), 1.f);
        o.z = fminf(fmaxf(hbB1.z + scB * hh1.z, -1.f), 1.f);
        o.w = fminf(fmaxf(hbB1.w + scB * hh1.w, -1.f), 1.f);
        __builtin_nontemporal_store(o, dstB + lane + 64);
    }
}

extern "C" void kernel_launch(void* const* d_in, const int* in_sizes, int n_in,
                              void* d_out, int out_size, void* d_ws, size_t ws_size,
                              hipStream_t stream) {
    const float* inputs = (const float*)d_in[0];
    const float* hidden = (const float*)d_in[1];
    const float* hebb   = (const float*)d_in[2];
    const float* Wi     = (const float*)d_in[3];
    const float* bi     = (const float*)d_in[4];
    const float* w      = (const float*)d_in[5];
    const float* alpha  = (const float*)d_in[6];
    const float* Wo     = (const float*)d_in[7];
    const float* bo     = (const float*)d_in[8];
    const float* Wv     = (const float*)d_in[9];
    const float* bv     = (const float*)d_in[10];
    const float* Wda    = (const float*)d_in[11];
    const float* bda    = (const float*)d_in[12];

    float* out = (float*)d_out;
    float* activout = out;                       // [256,4]   = 1024
    float* valueout = out + 1024;                // [256,1]   = 256
    float* daout    = out + 1280;                // [256,1]   = 256
    float* hactiv   = out + 1536;                // [256,512] = 131072
    float* hebb_new = out + 1536 + BS * HS;      // [256,512,512]

    float* acc  = (float*)d_ws;                          // 24 KB
    int* count  = (int*)((char*)d_ws + BS * BPB * 6 * 4);
    int* flag   = count + BS;

    // zero sync region each call (graph-safe, deterministic)
    hipMemsetAsync(count, 0, 2 * BS * sizeof(int), stream);

    fused_kernel<<<BS * BPB, 256, 0, stream>>>(inputs, hidden, hebb, Wi, bi, w,
                                               alpha, Wo, bo, Wv, bv, Wda, bda,
                                               activout, valueout, daout, hactiv,
                                               hebb_new, acc, count, flag);
}